// Round 8
// baseline (164.687 us; speedup 1.0000x reference)
//
#include <hip/hip_runtime.h>

// Problem constants (fixed-shape problem):
// h: (2,1,1,16,16) fp32   = 512
// gi: (2,M,1,16)   fp32   (e = gi[0], f = gi[1], row-major m*16+i)
// gj: (2,1,M,16)   fp32   (a = gj[0], b = gj[1], row-major m*16+j)
// theta: (2,M)     fp32
// out: (2,16,16)   fp32   = 512 (re block then im block)
//
// ROOFLINE NOTE (R1-R7 evidence): all structures (VGPR-load ILP, barrier LDS
// double-buffer, wave-private vmcnt pipeline, scalar vs packed FMA, 2-8
// blocks/CU) converge to ~220-240 cyc per 1KB wave-load per CU = 2.5-2.75 TB/s
// device read rate. m13 copy (~3.15 TB/s read half) and m146 RMSNorm
// (~2.44 TB/s read half) bracket this: it is the per-direction stream ceiling.
// This file = R4 kernel (best measured: 46.9-48.9 us, absmax 0).

constexpr int MDIM    = 524288;
constexpr int THREADS = 256;
constexpr int BLOCKS  = 2048;                     // 8 blocks/CU
constexpr int SLOTS   = BLOCKS * THREADS / 16;    // 32768 m-slots; MDIM/(2*SLOTS) = 8 iters

// Occupancy history:
//  R2: __launch_bounds__(256,8) -> compiler forced 32 VGPR -> 299 MB spill, 199 us.
//  R3/R4: 64 VGPR, no spill, 48 us — the best measured configuration.
#define MAIN_BOUNDS __launch_bounds__(THREADS) __attribute__((amdgpu_waves_per_eu(4, 8)))

__device__ __forceinline__ void theta_step(
    const float4 e4, const float4 f4, const float4 a4, const float4 b4,
    const float c, const float s,
    float (&are)[4][4], float (&aim)[4][4])
{
    const float av[4] = {a4.x, a4.y, a4.z, a4.w};
    const float bv[4] = {b4.x, b4.y, b4.z, b4.w};
    const float ev[4] = {e4.x, e4.y, e4.z, e4.w};
    const float fv[4] = {f4.x, f4.y, f4.z, f4.w};
    float ure[4], uim[4];
#pragma unroll
    for (int j = 0; j < 4; ++j) {
        ure[j] = av[j] * c - bv[j] * s;   // u_re = a*cos(t0) - b*sin(t1)
        uim[j] = av[j] * s + bv[j] * c;   // u_im = a*sin(t1) + b*cos(t0)
    }
#pragma unroll
    for (int i = 0; i < 4; ++i) {
#pragma unroll
        for (int j = 0; j < 4; ++j) {
            are[i][j] += ev[i] * ure[j] - fv[i] * uim[j];
            aim[i][j] += ev[i] * uim[j] + fv[i] * ure[j];
        }
    }
}

template <bool USE_ATOMIC>
__device__ __forceinline__ void theta_body(
    const float* __restrict__ gi, const float* __restrict__ gj,
    const float* __restrict__ theta, float* __restrict__ dst /* partial or out */)
{
    const int t    = threadIdx.x;
    const int g    = blockIdx.x * THREADS + t;
    const int tile = t & 15;                 // 16 tiles of 4x4 cover 16x16
    const int i0   = (tile >> 2) << 2;
    const int j0   = (tile & 3) << 2;
    const int slot = g >> 4;                 // lane bits 4,5 give wave m-parallelism

    const float* e_base = gi + i0;
    const float* f_base = gi + MDIM * 16 + i0;
    const float* a_base = gj + j0;
    const float* b_base = gj + MDIM * 16 + j0;

    float are[4][4] = {{0.f}};
    float aim[4][4] = {{0.f}};

    for (int m = slot; m < MDIM; m += 2 * SLOTS) {
        const int m2 = m + SLOTS;
        const float4 e0 = *(const float4*)(e_base + m * 16);
        const float4 f0 = *(const float4*)(f_base + m * 16);
        const float4 a0 = *(const float4*)(a_base + m * 16);
        const float4 b0 = *(const float4*)(b_base + m * 16);
        const float t00 = theta[m];
        const float t10 = theta[MDIM + m];
        const float4 e1 = *(const float4*)(e_base + m2 * 16);
        const float4 f1 = *(const float4*)(f_base + m2 * 16);
        const float4 a1 = *(const float4*)(a_base + m2 * 16);
        const float4 b1 = *(const float4*)(b_base + m2 * 16);
        const float t01 = theta[m2];
        const float t11 = theta[MDIM + m2];

        const float c0 = __cosf(t00), s0 = __sinf(t10);
        theta_step(e0, f0, a0, b0, c0, s0, are, aim);
        const float c1 = __cosf(t01), s1 = __sinf(t11);
        theta_step(e1, f1, a1, b1, c1, s1, are, aim);
    }

    // Fold the 4 m-lanes (lane bits 4,5) via butterfly shuffles.
#pragma unroll
    for (int i = 0; i < 4; ++i)
#pragma unroll
        for (int j = 0; j < 4; ++j) {
            are[i][j] += __shfl_xor(are[i][j], 16);
            are[i][j] += __shfl_xor(are[i][j], 32);
            aim[i][j] += __shfl_xor(aim[i][j], 16);
            aim[i][j] += __shfl_xor(aim[i][j], 32);
        }

    // Fold the 4 waves via LDS.
    __shared__ float red[4][16][33];
    const int wave = t >> 6;
    const int lane = t & 63;
    if (lane < 16) {
#pragma unroll
        for (int i = 0; i < 4; ++i)
#pragma unroll
            for (int j = 0; j < 4; ++j) {
                red[wave][lane][i * 4 + j]      = are[i][j];
                red[wave][lane][16 + i * 4 + j] = aim[i][j];
            }
    }
    __syncthreads();

    // 512 entries (16 tiles x 32 values); each thread finishes 2.
#pragma unroll
    for (int k = 0; k < 2; ++k) {
        const int idx = t * 2 + k;
        const int tl  = idx >> 5;
        const int v   = idx & 31;
        const float sum = red[0][tl][v] + red[1][tl][v] + red[2][tl][v] + red[3][tl][v];
        const int ii  = ((tl >> 2) << 2) + ((v & 15) >> 2);
        const int jj  = ((tl & 3) << 2) + (v & 3);
        const int off = ((v & 16) ? 256 : 0) + ii * 16 + jj;
        if (USE_ATOMIC) atomicAdd(dst + off, sum);
        else            dst[blockIdx.x * 512 + off] = sum;
    }
}

__global__ MAIN_BOUNDS void theta_main_ws(
    const float* __restrict__ gi, const float* __restrict__ gj,
    const float* __restrict__ theta, float* __restrict__ partial)
{
    theta_body<false>(gi, gj, theta, partial);
}

__global__ MAIN_BOUNDS void theta_main_atomic(
    const float* __restrict__ gi, const float* __restrict__ gj,
    const float* __restrict__ theta, float* __restrict__ out)
{
    theta_body<true>(gi, gj, theta, out);
}

// Stage 2: one wave per output element; fold BLOCKS partials + h bias.
__global__ __launch_bounds__(256) void theta_reduce(
    const float* __restrict__ h, const float* __restrict__ partial,
    float* __restrict__ out)
{
    const int w    = (blockIdx.x * 256 + threadIdx.x) >> 6;  // output index 0..511
    const int lane = threadIdx.x & 63;
    float s = 0.f;
#pragma unroll 8
    for (int j = 0; j < BLOCKS / 64; ++j)
        s += partial[(size_t)(j * 64 + lane) * 512 + w];
#pragma unroll
    for (int d = 1; d < 64; d <<= 1) s += __shfl_xor(s, d);
    if (lane == 0) out[w] = h[w] + s;
}

__global__ void theta_init(const float* __restrict__ h, float* __restrict__ out) {
    int k = blockIdx.x * blockDim.x + threadIdx.x;
    if (k < 512) out[k] = h[k];
}

extern "C" void kernel_launch(void* const* d_in, const int* in_sizes, int n_in,
                              void* d_out, int out_size, void* d_ws, size_t ws_size,
                              hipStream_t stream) {
    const float* h     = (const float*)d_in[0];
    const float* gi    = (const float*)d_in[1];
    const float* gj    = (const float*)d_in[2];
    const float* theta = (const float*)d_in[3];
    float* out = (float*)d_out;

    const size_t need = (size_t)BLOCKS * 512 * sizeof(float);  // 4 MB of partials
    if (ws_size >= need) {
        float* partial = (float*)d_ws;
        theta_main_ws<<<BLOCKS, THREADS, 0, stream>>>(gi, gj, theta, partial);
        theta_reduce<<<128, 256, 0, stream>>>(h, partial, out);
    } else {
        theta_init<<<2, 256, 0, stream>>>(h, out);
        theta_main_atomic<<<BLOCKS, THREADS, 0, stream>>>(gi, gj, theta, out);
    }
}